// Round 5
// baseline (460.773 us; speedup 1.0000x reference)
//
#include <hip/hip_runtime.h>

#define B_SZ   4096
#define T_SZ   512
#define F_SZ   32
#define S_SZ   64
#define H_SZ   128
#define OUT_SZ 32
#define PH_SZ  6

typedef __attribute__((ext_vector_type(8))) short bf16x8;
typedef __attribute__((ext_vector_type(4))) float f32x4;

union FragU { uint u[4]; bf16x8 v; };

// one v_perm_b32: low16 = trunc-bf16(a), high16 = trunc-bf16(b)
__device__ __forceinline__ uint hi_pair(float a, float b) {
  return __builtin_amdgcn_perm(__float_as_uint(b), __float_as_uint(a), 0x07060302u);
}
// residual of a after removing the bf16 stored in w's low/high half
__device__ __forceinline__ float lo_lo(float a, uint w) {
  return a - __uint_as_float(w << 16);
}
__device__ __forceinline__ float lo_hi(float b, uint w) {
  return b - __uint_as_float(w & 0xffff0000u);
}

#define MFMA(a, b, c) __builtin_amdgcn_mfma_f32_16x16x32_bf16((a), (b), (c), 0, 0, 0)

// 28 MFMA/step, fully register-resident single-wave scan.
// K-permutation pi(32kh+8g+j) = 32kh+16*(j>>2)+4g+(j&3) applied to A's columns
// at load time makes each lane's next B-fragment = its own D outputs (no exchange).
__global__ __launch_bounds__(64) void ssm_wave_kernel(
    const float* __restrict__ x, const float* __restrict__ pl,
    const float* __restrict__ W_A, const float* __restrict__ W_B,
    const float* __restrict__ W_C, const float* __restrict__ b_C,
    const float* __restrict__ W_ctrl, const float* __restrict__ b_ctrl,
    const float* __restrict__ W1, const float* __restrict__ b1,
    const float* __restrict__ W2, const float* __restrict__ b2,
    float* __restrict__ out) {
  __shared__ __align__(16) float s_fin[16][68];
  __shared__ __align__(16) float s_obs[16][132];
  __shared__ __align__(16) float s_h1[16][132];

  const int lane = threadIdx.x & 63;
  const int l15  = lane & 15;          // batch col within tile
  const int g    = lane >> 4;          // k-group / D row group
  const int rb   = blockIdx.x * 16;
  const int rg   = rb + l15;
  const float SC = 2.8853900817779268f;  // 2*log2(e): folds tanh's 2x*log2e

  // ---- A frags: scaled by SC, hi+lo split, pi-permuted columns ----
  FragU Ah[4][2], Al[4][2], Wb[4];
#pragma unroll
  for (int t = 0; t < 4; ++t) {
#pragma unroll
    for (int kh = 0; kh < 2; ++kh) {
      const float* ap = W_A + (size_t)(16 * t + l15) * S_SZ + 32 * kh + 4 * g;
      float4 f0 = *(const float4*)ap;          // pi cols j=0..3
      float4 f1 = *(const float4*)(ap + 16);   // pi cols j=4..7
      f0.x *= SC; f0.y *= SC; f0.z *= SC; f0.w *= SC;
      f1.x *= SC; f1.y *= SC; f1.z *= SC; f1.w *= SC;
      FragU hi, lo;
      hi.u[0] = hi_pair(f0.x, f0.y); hi.u[1] = hi_pair(f0.z, f0.w);
      hi.u[2] = hi_pair(f1.x, f1.y); hi.u[3] = hi_pair(f1.z, f1.w);
      lo.u[0] = hi_pair(lo_lo(f0.x, hi.u[0]), lo_hi(f0.y, hi.u[0]));
      lo.u[1] = hi_pair(lo_lo(f0.z, hi.u[1]), lo_hi(f0.w, hi.u[1]));
      lo.u[2] = hi_pair(lo_lo(f1.x, hi.u[2]), lo_hi(f1.y, hi.u[2]));
      lo.u[3] = hi_pair(lo_lo(f1.z, hi.u[3]), lo_hi(f1.w, hi.u[3]));
      Ah[t][kh] = hi; Al[t][kh] = lo;
    }
    // W_B: single truncated-bf16 plane (error zero-mean iid over t), scaled
    const float* wp = W_B + (size_t)(16 * t + l15) * F_SZ + 8 * g;
    float4 b0 = *(const float4*)wp;
    float4 b1v = *(const float4*)(wp + 4);
    b0.x *= SC; b0.y *= SC; b0.z *= SC; b0.w *= SC;
    b1v.x *= SC; b1v.y *= SC; b1v.z *= SC; b1v.w *= SC;
    Wb[t].u[0] = hi_pair(b0.x, b0.y);  Wb[t].u[1] = hi_pair(b0.z, b0.w);
    Wb[t].u[2] = hi_pair(b1v.x, b1v.y); Wb[t].u[3] = hi_pair(b1v.z, b1v.w);
  }

  // ---- control (scaled): lane holds states 16t+4g+q for batch rg ----
  float plv[PH_SZ];
#pragma unroll
  for (int p = 0; p < PH_SZ; ++p) plv[p] = pl[(size_t)rg * PH_SZ + p];
  f32x4 ctrl[4];
#pragma unroll
  for (int t = 0; t < 4; ++t) {
#pragma unroll
    for (int q = 0; q < 4; ++q) {
      const int i = 16 * t + 4 * g + q;
      float c = b_ctrl[i];
#pragma unroll
      for (int p = 0; p < PH_SZ; ++p) c = fmaf(W_ctrl[i * PH_SZ + p], plv[p], c);
      ctrl[t][q] = c * SC;
    }
  }

  // ---- scan state (all registers) ----
  const float* xg = x + (size_t)rg * T_SZ * F_SZ + 8 * g;
  bf16x8 sh0 = {0,0,0,0,0,0,0,0}, sh1 = sh0, sl0 = sh0, sl1 = sh0;
  const f32x4 zero4 = {0.f, 0.f, 0.f, 0.f};
  float4 xA0 = *(const float4*)(xg);
  float4 xA1 = *(const float4*)(xg + 4);
  float4 xB0 = *(const float4*)(xg + F_SZ);
  float4 xB1 = *(const float4*)(xg + F_SZ + 4);

#define STEP(T_, X0_, X1_, LAST_)                                              \
  {                                                                            \
    FragU xf;                                                                  \
    xf.u[0] = hi_pair(X0_.x, X0_.y); xf.u[1] = hi_pair(X0_.z, X0_.w);          \
    xf.u[2] = hi_pair(X1_.x, X1_.y); xf.u[3] = hi_pair(X1_.z, X1_.w);          \
    {                                                                          \
      const int tn_ = ((T_) + 2) & (T_SZ - 1);                                 \
      X0_ = *(const float4*)(xg + (size_t)tn_ * F_SZ);                         \
      X1_ = *(const float4*)(xg + (size_t)tn_ * F_SZ + 4);                     \
    }                                                                          \
    f32x4 P[4], Q[4];                                                          \
    _Pragma("unroll") for (int t = 0; t < 4; ++t)                              \
      P[t] = MFMA(Ah[t][0].v, sh0, ctrl[t]);                                   \
    _Pragma("unroll") for (int t = 0; t < 4; ++t)                              \
      Q[t] = MFMA(Al[t][0].v, sh0, zero4);                                     \
    _Pragma("unroll") for (int t = 0; t < 4; ++t)                              \
      P[t] = MFMA(Ah[t][1].v, sh1, P[t]);                                      \
    _Pragma("unroll") for (int t = 0; t < 4; ++t)                              \
      Q[t] = MFMA(Al[t][1].v, sh1, Q[t]);                                      \
    _Pragma("unroll") for (int t = 0; t < 4; ++t)                              \
      P[t] = MFMA(Wb[t].v, xf.v, P[t]);                                        \
    _Pragma("unroll") for (int t = 0; t < 4; ++t)                              \
      Q[t] = MFMA(Ah[t][0].v, sl0, Q[t]);                                      \
    _Pragma("unroll") for (int t = 0; t < 4; ++t)                              \
      Q[t] = MFMA(Ah[t][1].v, sl1, Q[t]);                                      \
    float v[4][4];                                                             \
    _Pragma("unroll") for (int t = 0; t < 4; ++t)                              \
    _Pragma("unroll") for (int q = 0; q < 4; ++q) {                            \
      float z = P[t][q] + Q[t][q];                                             \
      float e = __builtin_amdgcn_exp2f(z);                                     \
      v[t][q] = fmaf(-2.0f, __builtin_amdgcn_rcpf(e + 1.0f), 1.0f);            \
    }                                                                          \
    uint hw[4][2], lw[4][2];                                                   \
    _Pragma("unroll") for (int t = 0; t < 4; ++t) {                            \
      hw[t][0] = hi_pair(v[t][0], v[t][1]);                                    \
      hw[t][1] = hi_pair(v[t][2], v[t][3]);                                    \
      lw[t][0] = hi_pair(lo_lo(v[t][0], hw[t][0]), lo_hi(v[t][1], hw[t][0]));  \
      lw[t][1] = hi_pair(lo_lo(v[t][2], hw[t][1]), lo_hi(v[t][3], hw[t][1]));  \
    }                                                                          \
    FragU nh0, nh1, nl0, nl1;                                                  \
    nh0.u[0] = hw[0][0]; nh0.u[1] = hw[0][1]; nh0.u[2] = hw[1][0]; nh0.u[3] = hw[1][1]; \
    nh1.u[0] = hw[2][0]; nh1.u[1] = hw[2][1]; nh1.u[2] = hw[3][0]; nh1.u[3] = hw[3][1]; \
    nl0.u[0] = lw[0][0]; nl0.u[1] = lw[0][1]; nl0.u[2] = lw[1][0]; nl0.u[3] = lw[1][1]; \
    nl1.u[0] = lw[2][0]; nl1.u[1] = lw[2][1]; nl1.u[2] = lw[3][0]; nl1.u[3] = lw[3][1]; \
    sh0 = nh0.v; sh1 = nh1.v; sl0 = nl0.v; sl1 = nl1.v;                        \
    if (LAST_) {                                                               \
      _Pragma("unroll") for (int t = 0; t < 4; ++t)                            \
        *(float4*)(&s_fin[l15][16 * t + 4 * g]) =                              \
            make_float4(v[t][0], v[t][1], v[t][2], v[t][3]);                   \
    }                                                                          \
  }

  for (int t = 0; t < T_SZ; t += 2) {
    STEP(t,     xA0, xA1, false)
    STEP(t + 1, xB0, xB1, (t == T_SZ - 2))
  }
#undef STEP

  // ---- tail (single wave, no barriers; DS ops are in-order within a wave) ----
  asm volatile("" ::: "memory");
  // observation = W_C @ s + b_C : lane handles row l15, h = 4k+g
#pragma unroll 4
  for (int k = 0; k < 32; ++k) {
    const int h = 4 * k + g;
    float acc = b_C[h];
    const float4* wc = (const float4*)(W_C + (size_t)h * S_SZ);
    const float4* sv = (const float4*)(&s_fin[l15][0]);
#pragma unroll
    for (int j = 0; j < S_SZ / 4; ++j) {
      float4 w = wc[j]; float4 s = sv[j];
      acc = fmaf(w.x, s.x, acc); acc = fmaf(w.y, s.y, acc);
      acc = fmaf(w.z, s.z, acc); acc = fmaf(w.w, s.w, acc);
    }
    s_obs[l15][h] = acc;
  }
  asm volatile("" ::: "memory");
  // h1 = relu(W1 @ obs + b1)
#pragma unroll 4
  for (int k = 0; k < 32; ++k) {
    const int h = 4 * k + g;
    float acc = b1[h];
    const float4* w1p = (const float4*)(W1 + (size_t)h * H_SZ);
    const float4* ov  = (const float4*)(&s_obs[l15][0]);
#pragma unroll
    for (int j = 0; j < H_SZ / 4; ++j) {
      float4 w = w1p[j]; float4 o = ov[j];
      acc = fmaf(w.x, o.x, acc); acc = fmaf(w.y, o.y, acc);
      acc = fmaf(w.z, o.z, acc); acc = fmaf(w.w, o.w, acc);
    }
    s_h1[l15][h] = fmaxf(acc, 0.0f);
  }
  asm volatile("" ::: "memory");
  // out = W2 @ h1 + b2
#pragma unroll
  for (int k = 0; k < 8; ++k) {
    const int o = 4 * k + g;
    float acc = b2[o];
    const float4* w2p = (const float4*)(W2 + (size_t)o * H_SZ);
    const float4* hv  = (const float4*)(&s_h1[l15][0]);
#pragma unroll
    for (int j = 0; j < H_SZ / 4; ++j) {
      float4 w = w2p[j]; float4 h = hv[j];
      acc = fmaf(w.x, h.x, acc); acc = fmaf(w.y, h.y, acc);
      acc = fmaf(w.z, h.z, acc); acc = fmaf(w.w, h.w, acc);
    }
    out[(size_t)rg * OUT_SZ + o] = acc;
  }
}

extern "C" void kernel_launch(void* const* d_in, const int* in_sizes, int n_in,
                              void* d_out, int out_size, void* d_ws, size_t ws_size,
                              hipStream_t stream) {
  (void)in_sizes; (void)n_in; (void)out_size; (void)d_ws; (void)ws_size;
  const float* x      = (const float*)d_in[0];
  const float* pl     = (const float*)d_in[1];
  const float* W_A    = (const float*)d_in[2];
  const float* W_B    = (const float*)d_in[3];
  const float* W_C    = (const float*)d_in[4];
  const float* b_C    = (const float*)d_in[5];
  const float* W_ctrl = (const float*)d_in[6];
  const float* b_ctrl = (const float*)d_in[7];
  const float* W1     = (const float*)d_in[8];
  const float* b1     = (const float*)d_in[9];
  const float* W2     = (const float*)d_in[10];
  const float* b2     = (const float*)d_in[11];
  float* out = (float*)d_out;

  dim3 grid(B_SZ / 16);
  dim3 block(64);
  hipLaunchKernelGGL(ssm_wave_kernel, grid, block, 0, stream,
                     x, pl, W_A, W_B, W_C, b_C, W_ctrl, b_ctrl,
                     W1, b1, W2, b2, out);
}

// Round 6
// 369.464 us; speedup vs baseline: 1.2471x; 1.2471x over previous
//
#include <hip/hip_runtime.h>

#define B_SZ   4096
#define T_SZ   512
#define F_SZ   32
#define S_SZ   64
#define H_SZ   128
#define OUT_SZ 32
#define PH_SZ  6

#define ROWS    16
#define THREADS 256  // 4 waves; wave wv owns output states [16wv, 16wv+16)

typedef __attribute__((ext_vector_type(8))) short bf16x8;
typedef __attribute__((ext_vector_type(4))) float f32x4;

union FragU { uint u[4]; bf16x8 v; };

// one v_perm_b32: low16 = trunc-bf16(a), high16 = trunc-bf16(b)
__device__ __forceinline__ uint hi_pair(float a, float b) {
  return __builtin_amdgcn_perm(__float_as_uint(b), __float_as_uint(a), 0x07060302u);
}
__device__ __forceinline__ float lo_lo(float a, uint w) {
  return a - __uint_as_float(w << 16);
}
__device__ __forceinline__ float lo_hi(float b, uint w) {
  return b - __uint_as_float(w & 0xffff0000u);
}

#define MFMA(a, b, c) __builtin_amdgcn_mfma_f32_16x16x32_bf16((a), (b), (c), 0, 0, 0)

// barrier WITHOUT vmcnt drain: LDS writes visible, global prefetch stays in flight
#define WAVE_BARRIER() do { \
    asm volatile("s_waitcnt lgkmcnt(0)" ::: "memory"); \
    __builtin_amdgcn_s_barrier(); \
    asm volatile("" ::: "memory"); \
  } while (0)

__global__ __launch_bounds__(THREADS, 2) void ssm_hybrid_kernel(
    const float* __restrict__ x, const float* __restrict__ pl,
    const float* __restrict__ W_A, const float* __restrict__ W_B,
    const float* __restrict__ W_C, const float* __restrict__ b_C,
    const float* __restrict__ W_ctrl, const float* __restrict__ b_ctrl,
    const float* __restrict__ W1, const float* __restrict__ b1,
    const float* __restrict__ W2, const float* __restrict__ b2,
    float* __restrict__ out) {
  // state exchange: [buf][plane hi/lo][chunk 0..7][row 0..15][16B], XOR-swizzled
  __shared__ __align__(16) char  s_state[2][2][2048];
  __shared__ __align__(16) float s_final[ROWS][68];
  __shared__ __align__(16) float s_obs[ROWS][132];
  __shared__ __align__(16) float s_h1[ROWS][132];

  const int tid  = threadIdx.x;
  const int lane = tid & 63;
  const int wv   = tid >> 6;
  const int l15  = lane & 15;
  const int g    = lane >> 4;
  const int rb   = blockIdx.x * ROWS;
  const int rg   = rb + l15;
  const float SC = 2.8853900817779268f;  // 2*log2(e): folds tanh's exp arg

  // ---- weight frags (SC-scaled; A hi+lo split, Wb hi only) ----
  FragU Ah0, Al0, Ah1, Al1, Wb;
  {
#pragma unroll
    for (int kh = 0; kh < 2; ++kh) {
      const float* ap = W_A + (size_t)(16 * wv + l15) * S_SZ + 32 * kh + 8 * g;
      float4 f0 = *(const float4*)ap;
      float4 f1 = *(const float4*)(ap + 4);
      f0.x *= SC; f0.y *= SC; f0.z *= SC; f0.w *= SC;
      f1.x *= SC; f1.y *= SC; f1.z *= SC; f1.w *= SC;
      FragU hi, lo;
      hi.u[0] = hi_pair(f0.x, f0.y); hi.u[1] = hi_pair(f0.z, f0.w);
      hi.u[2] = hi_pair(f1.x, f1.y); hi.u[3] = hi_pair(f1.z, f1.w);
      lo.u[0] = hi_pair(lo_lo(f0.x, hi.u[0]), lo_hi(f0.y, hi.u[0]));
      lo.u[1] = hi_pair(lo_lo(f0.z, hi.u[1]), lo_hi(f0.w, hi.u[1]));
      lo.u[2] = hi_pair(lo_lo(f1.x, hi.u[2]), lo_hi(f1.y, hi.u[2]));
      lo.u[3] = hi_pair(lo_lo(f1.z, hi.u[3]), lo_hi(f1.w, hi.u[3]));
      if (kh == 0) { Ah0 = hi; Al0 = lo; } else { Ah1 = hi; Al1 = lo; }
    }
    const float* wp = W_B + (size_t)(16 * wv + l15) * F_SZ + 8 * g;
    float4 b0 = *(const float4*)wp;
    float4 b1v = *(const float4*)(wp + 4);
    b0.x *= SC; b0.y *= SC; b0.z *= SC; b0.w *= SC;
    b1v.x *= SC; b1v.y *= SC; b1v.z *= SC; b1v.w *= SC;
    Wb.u[0] = hi_pair(b0.x, b0.y);  Wb.u[1] = hi_pair(b0.z, b0.w);
    Wb.u[2] = hi_pair(b1v.x, b1v.y); Wb.u[3] = hi_pair(b1v.z, b1v.w);
  }

  // ---- control (SC-scaled), C/D layout: lane holds states 16wv+4g+q, col rg ----
  f32x4 ctrl;
#pragma unroll
  for (int q = 0; q < 4; ++q) {
    const int i = 16 * wv + 4 * g + q;
    float c = b_ctrl[i];
#pragma unroll
    for (int p = 0; p < PH_SZ; ++p)
      c = fmaf(W_ctrl[i * PH_SZ + p], pl[(size_t)rg * PH_SZ + p], c);
    ctrl[q] = c * SC;
  }

  // x addressing: lane reads x[rg][t][8g .. 8g+7]
  const float* xg = x + (size_t)rg * T_SZ * F_SZ + 8 * g;

  // LDS exchange offsets (XOR-swizzled, natural k-order)
  const int cw     = 2 * wv + (g >> 1);
  const int wr_off = cw * 256 + ((l15 * 16) ^ ((cw & 3) << 4)) + (g & 1) * 8;
  const int rsw    = (l15 * 16) ^ ((g & 3) << 4);
  const int rd0    = g * 256 + rsw;
  const int rd1    = (g + 4) * 256 + rsw;

  const f32x4 zero4 = {0.f, 0.f, 0.f, 0.f};
  bf16x8 sh0 = {0,0,0,0,0,0,0,0}, sh1 = sh0, sl0 = sh0, sl1 = sh0;

  // ---- prologue: base for t=0; prefetch x[1] (xB), x[2] (xA) ----
  f32x4 base;
  {
    float4 f0a = *(const float4*)(xg);
    float4 f0b = *(const float4*)(xg + 4);
    FragU xf;
    xf.u[0] = hi_pair(f0a.x, f0a.y); xf.u[1] = hi_pair(f0a.z, f0a.w);
    xf.u[2] = hi_pair(f0b.x, f0b.y); xf.u[3] = hi_pair(f0b.z, f0b.w);
    base = MFMA(Wb.v, xf.v, ctrl);
  }
  float4 xB0 = *(const float4*)(xg + F_SZ);
  float4 xB1 = *(const float4*)(xg + F_SZ + 4);
  float4 xA0 = *(const float4*)(xg + 2 * F_SZ);
  float4 xA1 = *(const float4*)(xg + 2 * F_SZ + 4);

  // STEP(T_): consume state T_ -> produce state T_+1; build base for T_+1
  // from X regs (holding x[T_+1]); reload X <- x[T_+3].
#define STEP(T_, X0_, X1_, NB_, LAST_)                                         \
  {                                                                            \
    f32x4 P  = MFMA(Ah0.v, sh0, base);                                         \
    f32x4 QA = MFMA(Al0.v, sh0, zero4);                                        \
    f32x4 QB = MFMA(Ah0.v, sl0, zero4);                                        \
    P  = MFMA(Ah1.v, sh1, P);                                                  \
    QA = MFMA(Al1.v, sh1, QA);                                                 \
    QB = MFMA(Ah1.v, sl1, QB);                                                 \
    float v0, v1, v2, v3;                                                      \
    {                                                                          \
      float z0 = P[0] + (QA[0] + QB[0]);                                       \
      float z1 = P[1] + (QA[1] + QB[1]);                                       \
      float z2 = P[2] + (QA[2] + QB[2]);                                       \
      float z3 = P[3] + (QA[3] + QB[3]);                                       \
      v0 = fmaf(-2.0f, __builtin_amdgcn_rcpf(__builtin_amdgcn_exp2f(z0) + 1.0f), 1.0f); \
      v1 = fmaf(-2.0f, __builtin_amdgcn_rcpf(__builtin_amdgcn_exp2f(z1) + 1.0f), 1.0f); \
      v2 = fmaf(-2.0f, __builtin_amdgcn_rcpf(__builtin_amdgcn_exp2f(z2) + 1.0f), 1.0f); \
      v3 = fmaf(-2.0f, __builtin_amdgcn_rcpf(__builtin_amdgcn_exp2f(z3) + 1.0f), 1.0f); \
    }                                                                          \
    const uint hp0 = hi_pair(v0, v1), hp1 = hi_pair(v2, v3);                   \
    const uint lp0 = hi_pair(lo_lo(v0, hp0), lo_hi(v1, hp0));                  \
    const uint lp1 = hi_pair(lo_lo(v2, hp1), lo_hi(v3, hp1));                  \
    *(uint2*)(&s_state[NB_][0][wr_off]) = make_uint2(hp0, hp1);                \
    *(uint2*)(&s_state[NB_][1][wr_off]) = make_uint2(lp0, lp1);                \
    if (LAST_)                                                                 \
      *(float4*)(&s_final[l15][16 * wv + 4 * g]) = make_float4(v0, v1, v2, v3);\
    WAVE_BARRIER();                                                            \
    sh0 = *(const bf16x8*)(&s_state[NB_][0][rd0]);                             \
    sh1 = *(const bf16x8*)(&s_state[NB_][0][rd1]);                             \
    sl0 = *(const bf16x8*)(&s_state[NB_][1][rd0]);                             \
    sl1 = *(const bf16x8*)(&s_state[NB_][1][rd1]);                             \
    /* next base (scheduled in ds_read shadow) */                              \
    FragU xf;                                                                  \
    xf.u[0] = hi_pair(X0_.x, X0_.y); xf.u[1] = hi_pair(X0_.z, X0_.w);          \
    xf.u[2] = hi_pair(X1_.x, X1_.y); xf.u[3] = hi_pair(X1_.z, X1_.w);          \
    {                                                                          \
      const int tn_ = ((T_) + 3) & (T_SZ - 1);                                 \
      X0_ = *(const float4*)(xg + (size_t)tn_ * F_SZ);                         \
      X1_ = *(const float4*)(xg + (size_t)tn_ * F_SZ + 4);                     \
    }                                                                          \
    base = MFMA(Wb.v, xf.v, ctrl);                                             \
  }

  for (int t = 0; t < T_SZ; t += 2) {
    STEP(t,     xB0, xB1, 1, false)
    STEP(t + 1, xA0, xA1, 0, (t == T_SZ - 2))
  }
#undef STEP

  // ---- tail projections ----
  __syncthreads();
  const int rt = tid >> 4;
  const int ct = tid & 15;

#pragma unroll
  for (int k = 0; k < 8; ++k) {
    const int h = ct + 16 * k;
    float acc = b_C[h];
    const float4* wc = (const float4*)(W_C + (size_t)h * S_SZ);
    const float4* sv = (const float4*)(&s_final[rt][0]);
#pragma unroll
    for (int j = 0; j < S_SZ / 4; ++j) {
      float4 w = wc[j]; float4 s = sv[j];
      acc = fmaf(w.x, s.x, acc); acc = fmaf(w.y, s.y, acc);
      acc = fmaf(w.z, s.z, acc); acc = fmaf(w.w, s.w, acc);
    }
    s_obs[rt][h] = acc;
  }
  __syncthreads();

#pragma unroll
  for (int k = 0; k < 8; ++k) {
    const int h = ct + 16 * k;
    float acc = b1[h];
    const float4* w1p = (const float4*)(W1 + (size_t)h * H_SZ);
    const float4* ov  = (const float4*)(&s_obs[rt][0]);
#pragma unroll
    for (int j = 0; j < H_SZ / 4; ++j) {
      float4 w = w1p[j]; float4 o = ov[j];
      acc = fmaf(w.x, o.x, acc); acc = fmaf(w.y, o.y, acc);
      acc = fmaf(w.z, o.z, acc); acc = fmaf(w.w, o.w, acc);
    }
    s_h1[rt][h] = fmaxf(acc, 0.0f);
  }
  __syncthreads();

#pragma unroll
  for (int it = 0; it < 2; ++it) {
    const int idx = tid + 256 * it;
    const int r = idx >> 5;
    const int c = idx & 31;
    float acc = b2[c];
    const float4* w2p = (const float4*)(W2 + (size_t)c * H_SZ);
    const float4* hv  = (const float4*)(&s_h1[r][0]);
#pragma unroll
    for (int j = 0; j < H_SZ / 4; ++j) {
      float4 w = w2p[j]; float4 h = hv[j];
      acc = fmaf(w.x, h.x, acc); acc = fmaf(w.y, h.y, acc);
      acc = fmaf(w.z, h.z, acc); acc = fmaf(w.w, h.w, acc);
    }
    out[(size_t)(rb + r) * OUT_SZ + c] = acc;
  }
}

extern "C" void kernel_launch(void* const* d_in, const int* in_sizes, int n_in,
                              void* d_out, int out_size, void* d_ws, size_t ws_size,
                              hipStream_t stream) {
  (void)in_sizes; (void)n_in; (void)out_size; (void)d_ws; (void)ws_size;
  const float* x      = (const float*)d_in[0];
  const float* pl     = (const float*)d_in[1];
  const float* W_A    = (const float*)d_in[2];
  const float* W_B    = (const float*)d_in[3];
  const float* W_C    = (const float*)d_in[4];
  const float* b_C    = (const float*)d_in[5];
  const float* W_ctrl = (const float*)d_in[6];
  const float* b_ctrl = (const float*)d_in[7];
  const float* W1     = (const float*)d_in[8];
  const float* b1     = (const float*)d_in[9];
  const float* W2     = (const float*)d_in[10];
  const float* b2     = (const float*)d_in[11];
  float* out = (float*)d_out;

  dim3 grid(B_SZ / ROWS);
  dim3 block(THREADS);
  hipLaunchKernelGGL(ssm_hybrid_kernel, grid, block, 0, stream,
                     x, pl, W_A, W_B, W_C, b_C, W_ctrl, b_ctrl,
                     W1, b1, W2, b2, out);
}